// Round 5
// baseline (267.393 us; speedup 1.0000x reference)
//
#include <hip/hip_runtime.h>
#include <math.h>

#define BB 32
#define LL 512
#define DD 32
#define KK 6
#define OO 192
#define DM 512

typedef __fp16 h2 __attribute__((ext_vector_type(2)));
union F2H { float f; h2 h; };
__device__ __forceinline__ float asF(h2 h) { F2H u; u.h = h; return u.f; }
__device__ __forceinline__ h2 asH(float f) { F2H u; u.f = f; return u.h; }

// LDS layout (float slots) for fused kernel
#define CSTR  520
#define XCOL  0                 // 7 cols x 520 (f32); overlaid later by f16 rows 512x4
#define YDMB  3648              // 192 x 4 (packed y f16); overlaid by DEN/NUM 2x768
#define MEDO  5184
#define STDO  5191
#define SAO   5198
#define SCO   5204
#define LDSF  5216              // 20.9 KB

// ---------------------------------------------------------------------------
// Prep: coalesced tiled transposes.
//  S1 (512 blocks): x_date (b,l,dk)   -> xt  (b,dk,l)   [dk=d*6+k, 192]
//  S2 (128 blocks): x      (b,l,d)    -> xt2 (b,d,l)
//  S3 (128 blocks): y_date (b,o,dk)   -> yt  (b,d,o,k)
// ---------------------------------------------------------------------------
__global__ __launch_bounds__(256) void prep_kernel(
    const float* __restrict__ x, const float* __restrict__ x_date,
    const float* __restrict__ y_date,
    float* __restrict__ xt, float* __restrict__ xt2, float* __restrict__ yt) {
  __shared__ float tl[9408];
  int bid = blockIdx.x, tid = threadIdx.x;

  if (bid < 512) {
    // ---- S1: tile 32 l x 192 dk ----
    int b = bid >> 4, l0 = (bid & 15) * 32;
    const float* src = x_date + (size_t)(b * LL + l0) * 192;
    #pragma unroll
    for (int it = 0; it < 6; ++it) {            // 1536 float4 reads
      int f = tid + it * 256;
      int row = f / 48, c4 = f % 48;
      float4 v = ((const float4*)(src + (size_t)row * 192))[c4];
      float* p = &tl[row * 196 + c4 * 4];
      p[0] = v.x; p[1] = v.y; p[2] = v.z; p[3] = v.w;
    }
    __syncthreads();
    #pragma unroll
    for (int it = 0; it < 6; ++it) {            // 1536 float4 writes
      int f = tid + it * 256;
      int dk = f / 8, c4 = f % 8;
      float4 v;
      v.x = tl[(c4 * 4 + 0) * 196 + dk];
      v.y = tl[(c4 * 4 + 1) * 196 + dk];
      v.z = tl[(c4 * 4 + 2) * 196 + dk];
      v.w = tl[(c4 * 4 + 3) * 196 + dk];
      ((float4*)(xt + (size_t)(b * 192 + dk) * LL + l0))[c4] = v;
    }
  } else if (bid < 640) {
    // ---- S2: tile 128 l x 32 d ----
    int id = bid - 512;
    int b = id >> 2, l0 = (id & 3) * 128;
    const float* src = x + (size_t)(b * LL + l0) * DD;   // tile contiguous
    #pragma unroll
    for (int it = 0; it < 4; ++it) {            // 1024 float4
      int f = tid + it * 256;
      int row = f / 8, c4 = f % 8;
      float4 v = ((const float4*)src)[f];
      float* p = &tl[row * 36 + c4 * 4];
      p[0] = v.x; p[1] = v.y; p[2] = v.z; p[3] = v.w;
    }
    __syncthreads();
    #pragma unroll
    for (int it = 0; it < 4; ++it) {
      int f = tid + it * 256;
      int d = f / 32, c4 = f % 32;
      float4 v;
      v.x = tl[(c4 * 4 + 0) * 36 + d];
      v.y = tl[(c4 * 4 + 1) * 36 + d];
      v.z = tl[(c4 * 4 + 2) * 36 + d];
      v.w = tl[(c4 * 4 + 3) * 36 + d];
      ((float4*)(xt2 + (size_t)(b * DD + d) * LL + l0))[c4] = v;
    }
  } else {
    // ---- S3: tile 48 o x 192 dk ----
    int id = bid - 640;
    int b = id >> 2, o0 = (id & 3) * 48;
    const float* src = y_date + (size_t)(b * OO + o0) * 192;
    #pragma unroll
    for (int it = 0; it < 9; ++it) {            // 2304 float4
      int f = tid + it * 256;
      int row = f / 48, c4 = f % 48;
      float4 v = ((const float4*)(src + (size_t)row * 192))[c4];
      float* p = &tl[row * 196 + c4 * 4];
      p[0] = v.x; p[1] = v.y; p[2] = v.z; p[3] = v.w;
    }
    __syncthreads();
    #pragma unroll
    for (int it = 0; it < 9; ++it) {            // 32 d x 72 float4
      int f = tid + it * 256;
      int d = f / 72, r4 = f % 72;
      float4 v;
      #pragma unroll
      for (int j = 0; j < 4; ++j) {
        int e = r4 * 4 + j;
        int op = e / 6, k = e - op * 6;
        ((float*)&v)[j] = tl[op * 196 + d * 6 + k];
      }
      ((float4*)(yt + (size_t)(b * DD + d) * (OO * KK) + o0 * 6))[r4] = v;
    }
  }
}

// ---------------------------------------------------------------------------
// In-register bitonic sort of 512 floats across one wave (8 elems/lane).
// ---------------------------------------------------------------------------
__device__ __forceinline__ void sort512(float v[8], int lane) {
  #pragma unroll
  for (int k = 2; k <= 512; k <<= 1) {
    #pragma unroll
    for (int j = k >> 1; j > 0; j >>= 1) {
      if (j >= 8) {
        int jj = j >> 3;
        bool lower = (lane & jj) == 0;
        bool asc = ((lane << 3) & k) == 0;
        bool keepmin = (asc == lower);
        #pragma unroll
        for (int r = 0; r < 8; ++r) {
          float o = __shfl_xor(v[r], jj);
          v[r] = keepmin ? fminf(v[r], o) : fmaxf(v[r], o);
        }
      } else {
        #pragma unroll
        for (int r = 0; r < 8; ++r) {
          if ((r & j) == 0) {
            int r2 = r | j;
            bool asc = (((lane << 3) | r) & k) == 0;
            float a = v[r], b = v[r2];
            float lo = fminf(a, b), hi = fmaxf(a, b);
            v[r]  = asc ? lo : hi;
            v[r2] = asc ? hi : lo;
          }
        }
      }
    }
  }
}

// ---------------------------------------------------------------------------
// Fused: per-(b,d) order stats + affine map + attention + err + ymean.
// Inputs pre-transposed: all global reads coalesced.
// ---------------------------------------------------------------------------
__global__ __launch_bounds__(256) void fused_kernel(
    const float* __restrict__ xt, const float* __restrict__ xt2,
    const float* __restrict__ yt,
    float* __restrict__ V, float* __restrict__ ymean, float* __restrict__ errt) {
  __shared__ float lds[LDSF];
  int bid = blockIdx.x, b = bid >> 5, d = bid & 31;
  int tid = threadIdx.x, lane = tid & 63, wv = tid >> 6;

  // ---- stage 7 contiguous rows (6 x_date cols + x) into LDS columns ----
  const float* xtb  = xt  + (size_t)(b * 192 + d * 6) * LL;
  const float* xtb2 = xt2 + (size_t)(b * DD + d) * LL;
  #pragma unroll
  for (int it = 0; it < 4; ++it) {
    int f = tid + it * 256;
    if (f < 896) {
      int c = f >> 7, c4 = f & 127;
      const float* srow = (c < 6) ? (xtb + (size_t)c * LL) : xtb2;
      float4 v = ((const float4*)srow)[c4];
      *(float4*)&lds[XCOL + c * CSTR + c4 * 4] = v;
    }
  }
  __syncthreads();

  // ---- sort 7 sequences (2 passes of 4 waves) ----
  #pragma unroll
  for (int pass = 0; pass < 2; ++pass) {
    int s = pass * 4 + wv;
    if (s < 7) {
      float v[8];
      const float4* colp = (const float4*)&lds[XCOL + s * CSTR + lane * 8];
      float4 c0 = colp[0], c1 = colp[1];
      v[0]=c0.x; v[1]=c0.y; v[2]=c0.z; v[3]=c0.w;
      v[4]=c1.x; v[5]=c1.y; v[6]=c1.z; v[7]=c1.w;
      sort512(v, lane);
      float e127 = __shfl(v[7], 15);
      float e128 = __shfl(v[0], 16);
      float e255 = __shfl(v[7], 31);
      float e383 = __shfl(v[7], 47);
      float e384 = __shfl(v[0], 48);
      if (lane == 0) {
        float q25 = e127 + 0.75f * (e128 - e127);   // 0.25*(n-1)=127.75
        float q75 = e383 + 0.25f * (e384 - e383);   // 0.75*(n-1)=383.25
        lds[MEDO + s] = e255;                       // torch lower-median
        lds[STDO + s] = q75 - q25 + 1e-6f;
      }
    }
  }
  __syncthreads();

  if (tid < 6) {
    float a = lds[STDO + 6] / lds[STDO + tid];
    lds[SAO + tid] = a;
    lds[SCO + tid] = lds[MEDO + 6] - lds[MEDO + tid] * a;
  }
  __syncthreads();

  float ask[6], csk[6];
  #pragma unroll
  for (int k = 0; k < 6; ++k) { ask[k] = lds[SAO + k]; csk[k] = lds[SCO + k]; }

  const float PSC = 0.58912435f;   // (1/sqrt(6)) * log2(e)

  // ---- transform rows tid, tid+256 into regs (f16-packed, x-side prescaled) ----
  float4 packed[2];
  #pragma unroll
  for (int it = 0; it < 2; ++it) {
    int l = tid + it * 256;
    float m0 = ask[0]*lds[XCOL+0*CSTR+l] + csk[0];
    float m1 = ask[1]*lds[XCOL+1*CSTR+l] + csk[1];
    float m2 = ask[2]*lds[XCOL+2*CSTR+l] + csk[2];
    float m3 = ask[3]*lds[XCOL+3*CSTR+l] + csk[3];
    float m4 = ask[4]*lds[XCOL+4*CSTR+l] + csk[4];
    float m5 = ask[5]*lds[XCOL+5*CSTR+l] + csk[5];
    float xvv = lds[XCOL + 6*CSTR + l];
    errt[(size_t)bid * LL + l] = xvv - (m0+m1+m2+m3+m4+m5) * (1.0f/6.0f);
    packed[it].x = asF(__builtin_amdgcn_cvt_pkrtz(m0*PSC, m1*PSC));
    packed[it].y = asF(__builtin_amdgcn_cvt_pkrtz(m2*PSC, m3*PSC));
    packed[it].z = asF(__builtin_amdgcn_cvt_pkrtz(m4*PSC, m5*PSC));
    packed[it].w = asF(__builtin_amdgcn_cvt_pkrtz(xvv, 0.0f));
  }

  // ---- y staging (threads 0..191): coalesced yt reads, map, ymean, pack ----
  float4 ypk; float ymv; bool doY = (tid < OO);
  if (doY) {
    const float2* yp = (const float2*)(yt + (size_t)(b * DD + d) * (OO * KK) + tid * 6);
    float2 y0 = yp[0], y1 = yp[1], y2 = yp[2];
    float q0 = ask[0]*y0.x + csk[0];
    float q1 = ask[1]*y0.y + csk[1];
    float q2 = ask[2]*y1.x + csk[2];
    float q3 = ask[3]*y1.y + csk[3];
    float q4 = ask[4]*y2.x + csk[4];
    float q5 = ask[5]*y2.y + csk[5];
    ymv = (q0+q1+q2+q3+q4+q5) * (1.0f/6.0f);
    ypk.x = asF(__builtin_amdgcn_cvt_pkrtz(q0, q1));
    ypk.y = asF(__builtin_amdgcn_cvt_pkrtz(q2, q3));
    ypk.z = asF(__builtin_amdgcn_cvt_pkrtz(q4, q5));
  }
  __syncthreads();   // all XCOL reads done; safe to overlay

  // ---- write f16 rows (overlay XCOL) + YDM; load yk frags ----
  *(float4*)&lds[tid * 4]         = packed[0];
  *(float4*)&lds[(tid + 256) * 4] = packed[1];
  if (doY) {
    ymean[(size_t)bid * OO + tid] = ymv;
    lds[YDMB + tid*4 + 0] = ypk.x;
    lds[YDMB + tid*4 + 1] = ypk.y;
    lds[YDMB + tid*4 + 2] = ypk.z;
  }
  __syncthreads();

  h2 yk[3][3];
  #pragma unroll
  for (int j = 0; j < 3; ++j) {
    int o = lane + 64 * j;
    yk[j][0] = asH(lds[YDMB + o*4 + 0]);
    yk[j][1] = asH(lds[YDMB + o*4 + 1]);
    yk[j][2] = asH(lds[YDMB + o*4 + 2]);
  }
  __syncthreads();   // yk loaded; DEN/NUM may overlay YDM after this

  // ---- attention: wave wv handles l in [wv*128, wv*128+128), 3 o's/lane ----
  float den[3] = {0.f,0.f,0.f}, num[3] = {0.f,0.f,0.f};
  int l0 = wv * 128;
  #pragma unroll 2
  for (int l = l0; l < l0 + 128; ++l) {
    float4 rw = *(const float4*)&lds[l * 4];
    h2 x01 = asH(rw.x), x23 = asH(rw.y), x45 = asH(rw.z);
    float xf = (float)(asH(rw.w).x);
    #pragma unroll
    for (int j = 0; j < 3; ++j) {
      float sc = __builtin_amdgcn_fdot2(x01, yk[j][0], 0.0f, false);
      sc = __builtin_amdgcn_fdot2(x23, yk[j][1], sc, false);
      sc = __builtin_amdgcn_fdot2(x45, yk[j][2], sc, false);
      float e = exp2f(sc);     // scale folded into x-side pack
      den[j] += e;
      num[j] += e * xf;
    }
  }
  #pragma unroll
  for (int j = 0; j < 3; ++j) {
    lds[YDMB + wv*192 + lane + 64*j]       = den[j];
    lds[YDMB + 768 + wv*192 + lane + 64*j] = num[j];
  }
  __syncthreads();
  if (tid < OO) {
    float dsum = lds[YDMB + tid] + lds[YDMB + 192 + tid]
               + lds[YDMB + 384 + tid] + lds[YDMB + 576 + tid];
    float nsum = lds[YDMB + 768 + tid] + lds[YDMB + 960 + tid]
               + lds[YDMB + 1152 + tid] + lds[YDMB + 1344 + tid];
    V[(size_t)bid * OO + tid] = nsum / dsum;
  }
}

// ---------------------------------------------------------------------------
// Gating MLP: 4 rows/block, 256 blocks, 256 threads, 2 m's per thread.
// 16-row double-buffered w1 prefetch (16 loads in flight) hides L2 latency.
// ---------------------------------------------------------------------------
__global__ __launch_bounds__(256) void mlp_kernel(
    const float* __restrict__ errt, const float* __restrict__ w1,
    const float* __restrict__ b1, const float* __restrict__ w2,
    const float* __restrict__ b2, float* __restrict__ w0out) {
  int r0 = blockIdx.x * 4;
  int tid = threadIdx.x;
  __shared__ float esh[4 * LL];     // 8 KB

  const float4* src = (const float4*)(errt + (size_t)r0 * LL);
  ((float4*)esh)[tid]       = src[tid];
  ((float4*)esh)[tid + 256] = src[tid + 256];

  float2 bb = ((const float2*)b1)[tid];
  float2 acc[4];
  #pragma unroll
  for (int r = 0; r < 4; ++r) acc[r] = bb;

  const float2* wp = (const float2*)w1 + tid;   // row l at wp[l*256]
  float2 buf[2][16];
  #pragma unroll
  for (int j = 0; j < 16; ++j) buf[0][j] = wp[j * 256];
  __syncthreads();

  for (int grp = 0; grp < 32; ++grp) {
    int cur = grp & 1, nxt = cur ^ 1;
    if (grp < 31) {
      #pragma unroll
      for (int j = 0; j < 16; ++j) buf[nxt][j] = wp[((grp + 1) * 16 + j) * 256];
    }
    int lb = grp * 16;
    #pragma unroll
    for (int r = 0; r < 4; ++r) {
      const float* er = &esh[r * LL + lb];
      #pragma unroll
      for (int q = 0; q < 4; ++q) {
        float4 e = *(const float4*)(er + q * 4);
        float2 w0v = buf[cur][q*4+0], w1v = buf[cur][q*4+1],
               w2v = buf[cur][q*4+2], w3v = buf[cur][q*4+3];
        acc[r].x += e.x * w0v.x; acc[r].y += e.x * w0v.y;
        acc[r].x += e.y * w1v.x; acc[r].y += e.y * w1v.y;
        acc[r].x += e.z * w2v.x; acc[r].y += e.z * w2v.y;
        acc[r].x += e.w * w3v.x; acc[r].y += e.w * w3v.y;
      }
    }
  }

  float4 w2v = ((const float4*)w2)[tid];   // [m0c0,m0c1,m1c0,m1c1]
  float w2d0 = w2v.x - w2v.y, w2d1 = w2v.z - w2v.w;
  float p[4];
  #pragma unroll
  for (int r = 0; r < 4; ++r) {
    float h0 = acc[r].x, h1 = acc[r].y;
    float g0 = 0.5f * h0 * (1.0f + erff(h0 * 0.70710678f));
    float g1 = 0.5f * h1 * (1.0f + erff(h1 * 0.70710678f));
    p[r] = g0 * w2d0 + g1 * w2d1;
  }
  #pragma unroll
  for (int r = 0; r < 4; ++r)
    for (int off = 32; off > 0; off >>= 1)
      p[r] += __shfl_down(p[r], off);

  __shared__ float part[4][4];
  int wave = tid >> 6, lane = tid & 63;
  if (lane == 0) {
    #pragma unroll
    for (int r = 0; r < 4; ++r) part[wave][r] = p[r];
  }
  __syncthreads();
  if (tid < 4) {
    float ld = b2[0] - b2[1] + part[0][tid] + part[1][tid] + part[2][tid] + part[3][tid];
    w0out[r0 + tid] = 1.0f / (1.0f + expf(-ld));
  }
}

// ---------------------------------------------------------------------------
__global__ __launch_bounds__(256) void bnstats_kernel(
    const float* __restrict__ V, float* __restrict__ mu, float* __restrict__ rstd) {
  int d = blockIdx.x;
  int tid = threadIdx.x;
  float s = 0.0f, s2 = 0.0f;
  for (int idx = tid; idx < BB * OO; idx += 256) {
    int b = idx / OO, o = idx - b * OO;
    float v = V[((size_t)b * DD + d) * OO + o];
    s += v; s2 += v * v;
  }
  for (int off = 32; off > 0; off >>= 1) {
    s  += __shfl_down(s, off);
    s2 += __shfl_down(s2, off);
  }
  __shared__ float ps[4], ps2[4];
  int wave = tid >> 6, lane = tid & 63;
  if (lane == 0) { ps[wave] = s; ps2[wave] = s2; }
  __syncthreads();
  if (tid == 0) {
    float S = ps[0] + ps[1] + ps[2] + ps[3];
    float S2 = ps2[0] + ps2[1] + ps2[2] + ps2[3];
    const float inv = 1.0f / (BB * OO);
    float mean = S * inv;
    float var = S2 * inv - mean * mean;
    mu[d] = mean;
    rstd[d] = rsqrtf(var + 1e-5f);
  }
}

// ---------------------------------------------------------------------------
// Final fusion via LDS transpose: coalesced reads AND writes.
// 64 blocks: (b, o-half of 96).
// ---------------------------------------------------------------------------
__global__ __launch_bounds__(256) void final_kernel(
    const float* __restrict__ V, const float* __restrict__ ymean,
    const float* __restrict__ w0, const float* __restrict__ mu,
    const float* __restrict__ rstd, const float* __restrict__ gamma,
    const float* __restrict__ beta, float* __restrict__ out) {
  __shared__ float vsh[32 * 100], ysh[32 * 100];
  __shared__ float gate[32], scal[32], offs[32];
  int bid = blockIdx.x, b = bid >> 1, o0 = (bid & 1) * 96;
  int tid = threadIdx.x;

  #pragma unroll
  for (int it = 0; it < 3; ++it) {        // 32 d x 24 float4
    int f = tid + it * 256;
    int d = f / 24, c4 = f % 24;
    size_t goff = (size_t)(b * DD + d) * OO + o0;
    float4 v = ((const float4*)(V + goff))[c4];
    float4 y = ((const float4*)(ymean + goff))[c4];
    float* pv = &vsh[d * 100 + c4 * 4];
    float* py = &ysh[d * 100 + c4 * 4];
    pv[0]=v.x; pv[1]=v.y; pv[2]=v.z; pv[3]=v.w;
    py[0]=y.x; py[1]=y.y; py[2]=y.z; py[3]=y.w;
  }
  if (tid < 32) {
    float g = gamma[tid] * rstd[tid];
    gate[tid] = w0[b * DD + tid];
    scal[tid] = g;
    offs[tid] = beta[tid] - mu[tid] * g;
  }
  __syncthreads();

  #pragma unroll
  for (int it = 0; it < 3; ++it) {        // 96 o x 8 float4
    int f = tid + it * 256;
    int op = f / 8, c4 = f % 8;
    float4 r;
    #pragma unroll
    for (int j = 0; j < 4; ++j) {
      int d = c4 * 4 + j;
      float v  = vsh[d * 100 + op];
      float ym = ysh[d * 100 + op];
      float g  = gate[d];
      float y  = v * scal[d] + offs[d];
      ((float*)&r)[j] = ym * g + y * (1.0f - g);
    }
    ((float4*)(out + (size_t)(b * OO + o0 + op) * DD))[c4] = r;
  }
}

// ---------------------------------------------------------------------------
extern "C" void kernel_launch(void* const* d_in, const int* in_sizes, int n_in,
                              void* d_out, int out_size, void* d_ws, size_t ws_size,
                              hipStream_t stream) {
  const float* x      = (const float*)d_in[0];
  const float* x_date = (const float*)d_in[1];
  const float* y_date = (const float*)d_in[2];
  const float* w1     = (const float*)d_in[3];
  const float* b1     = (const float*)d_in[4];
  const float* w2     = (const float*)d_in[5];
  const float* b2     = (const float*)d_in[6];
  const float* gamma  = (const float*)d_in[7];
  const float* beta   = (const float*)d_in[8];
  float* out = (float*)d_out;

  float* ws    = (float*)d_ws;
  float* V     = ws;                 // 196608  (B,D,O)
  float* ymean = ws + 196608;        // 196608  (B,D,O)
  float* errt  = ws + 393216;        // 524288  (B,D,L)
  float* w0    = ws + 917504;        // 1024    (B,D)
  float* mu    = ws + 918528;        // 32
  float* rstd  = ws + 918560;        // 32
  float* xt    = ws + 918592;        // 3145728 (B,192,L)
  float* xt2   = ws + 4064320;       // 524288  (B,D,L)
  float* yt    = ws + 4588608;       // 1179648 (B,D,O,K)

  prep_kernel<<<768, 256, 0, stream>>>(x, x_date, y_date, xt, xt2, yt);
  fused_kernel<<<BB * DD, 256, 0, stream>>>(xt, xt2, yt, V, ymean, errt);
  mlp_kernel<<<BB * DD / 4, 256, 0, stream>>>(errt, w1, b1, w2, b2, w0);
  bnstats_kernel<<<DD, 256, 0, stream>>>(V, mu, rstd);
  final_kernel<<<2 * BB, 256, 0, stream>>>(V, ymean, w0, mu, rstd, gamma, beta, out);
}

// Round 6
// 172.360 us; speedup vs baseline: 1.5514x; 1.5514x over previous
//
#include <hip/hip_runtime.h>
#include <math.h>

#define BB 32
#define LL 512
#define DD 32
#define KK 6
#define OO 192
#define DM 512

typedef __fp16 h2 __attribute__((ext_vector_type(2)));
union F2H { float f; h2 h; };
__device__ __forceinline__ float asF(h2 h) { F2H u; u.h = h; return u.f; }
__device__ __forceinline__ h2 asH(float f) { F2H u; u.f = f; return u.h; }

// LDS layout (float slots) for fused kernel
#define CSTR  520
#define XCOL  0                 // 7 cols x 520 (f32); overlaid later by f16 rows 512x4
#define YDMB  3648              // 192 x 4 (packed y f16); overlaid by DEN/NUM 2x768
#define MEDO  5184
#define STDO  5191
#define SAO   5198
#define SCO   5204
#define LDSF  5216              // 20.9 KB

// ---------------------------------------------------------------------------
// Prep: coalesced tiled transposes.
//  S1 (512 blocks): x_date (b,l,dk)   -> xt  (b,dk,l)   [dk=d*6+k, 192]
//  S2 (128 blocks): x      (b,l,d)    -> xt2 (b,d,l)
//  S3 (128 blocks): y_date (b,o,dk)   -> yt  (b,d,o,k)
// ---------------------------------------------------------------------------
__global__ __launch_bounds__(256) void prep_kernel(
    const float* __restrict__ x, const float* __restrict__ x_date,
    const float* __restrict__ y_date,
    float* __restrict__ xt, float* __restrict__ xt2, float* __restrict__ yt) {
  __shared__ float tl[9408];
  int bid = blockIdx.x, tid = threadIdx.x;

  if (bid < 512) {
    // ---- S1: tile 32 l x 192 dk ----
    int b = bid >> 4, l0 = (bid & 15) * 32;
    const float* src = x_date + (size_t)(b * LL + l0) * 192;
    #pragma unroll
    for (int it = 0; it < 6; ++it) {            // 1536 float4 reads
      int f = tid + it * 256;
      int row = f / 48, c4 = f % 48;
      float4 v = ((const float4*)(src + (size_t)row * 192))[c4];
      float* p = &tl[row * 196 + c4 * 4];
      p[0] = v.x; p[1] = v.y; p[2] = v.z; p[3] = v.w;
    }
    __syncthreads();
    #pragma unroll
    for (int it = 0; it < 6; ++it) {            // 1536 float4 writes
      int f = tid + it * 256;
      int dk = f / 8, c4 = f % 8;
      float4 v;
      v.x = tl[(c4 * 4 + 0) * 196 + dk];
      v.y = tl[(c4 * 4 + 1) * 196 + dk];
      v.z = tl[(c4 * 4 + 2) * 196 + dk];
      v.w = tl[(c4 * 4 + 3) * 196 + dk];
      ((float4*)(xt + (size_t)(b * 192 + dk) * LL + l0))[c4] = v;
    }
  } else if (bid < 640) {
    // ---- S2: tile 128 l x 32 d ----
    int id = bid - 512;
    int b = id >> 2, l0 = (id & 3) * 128;
    const float* src = x + (size_t)(b * LL + l0) * DD;   // tile contiguous
    #pragma unroll
    for (int it = 0; it < 4; ++it) {            // 1024 float4
      int f = tid + it * 256;
      int row = f / 8, c4 = f % 8;
      float4 v = ((const float4*)src)[f];
      float* p = &tl[row * 36 + c4 * 4];
      p[0] = v.x; p[1] = v.y; p[2] = v.z; p[3] = v.w;
    }
    __syncthreads();
    #pragma unroll
    for (int it = 0; it < 4; ++it) {
      int f = tid + it * 256;
      int d = f / 32, c4 = f % 32;
      float4 v;
      v.x = tl[(c4 * 4 + 0) * 36 + d];
      v.y = tl[(c4 * 4 + 1) * 36 + d];
      v.z = tl[(c4 * 4 + 2) * 36 + d];
      v.w = tl[(c4 * 4 + 3) * 36 + d];
      ((float4*)(xt2 + (size_t)(b * DD + d) * LL + l0))[c4] = v;
    }
  } else {
    // ---- S3: tile 48 o x 192 dk ----
    int id = bid - 640;
    int b = id >> 2, o0 = (id & 3) * 48;
    const float* src = y_date + (size_t)(b * OO + o0) * 192;
    #pragma unroll
    for (int it = 0; it < 9; ++it) {            // 2304 float4
      int f = tid + it * 256;
      int row = f / 48, c4 = f % 48;
      float4 v = ((const float4*)(src + (size_t)row * 192))[c4];
      float* p = &tl[row * 196 + c4 * 4];
      p[0] = v.x; p[1] = v.y; p[2] = v.z; p[3] = v.w;
    }
    __syncthreads();
    #pragma unroll
    for (int it = 0; it < 9; ++it) {            // 32 d x 72 float4
      int f = tid + it * 256;
      int d = f / 72, r4 = f % 72;
      float4 v;
      #pragma unroll
      for (int j = 0; j < 4; ++j) {
        int e = r4 * 4 + j;
        int op = e / 6, k = e - op * 6;
        ((float*)&v)[j] = tl[op * 196 + d * 6 + k];
      }
      ((float4*)(yt + (size_t)(b * DD + d) * (OO * KK) + o0 * 6))[r4] = v;
    }
  }
}

// ---------------------------------------------------------------------------
// In-register bitonic sort of 512 floats across one wave (8 elems/lane).
// ---------------------------------------------------------------------------
__device__ __forceinline__ void sort512(float v[8], int lane) {
  #pragma unroll
  for (int k = 2; k <= 512; k <<= 1) {
    #pragma unroll
    for (int j = k >> 1; j > 0; j >>= 1) {
      if (j >= 8) {
        int jj = j >> 3;
        bool lower = (lane & jj) == 0;
        bool asc = ((lane << 3) & k) == 0;
        bool keepmin = (asc == lower);
        #pragma unroll
        for (int r = 0; r < 8; ++r) {
          float o = __shfl_xor(v[r], jj);
          v[r] = keepmin ? fminf(v[r], o) : fmaxf(v[r], o);
        }
      } else {
        #pragma unroll
        for (int r = 0; r < 8; ++r) {
          if ((r & j) == 0) {
            int r2 = r | j;
            bool asc = (((lane << 3) | r) & k) == 0;
            float a = v[r], b = v[r2];
            float lo = fminf(a, b), hi = fmaxf(a, b);
            v[r]  = asc ? lo : hi;
            v[r2] = asc ? hi : lo;
          }
        }
      }
    }
  }
}

// ---------------------------------------------------------------------------
// Fused: per-(b,d) order stats + affine map + attention + err + ymean.
// Inputs pre-transposed: all global reads coalesced.
// ---------------------------------------------------------------------------
__global__ __launch_bounds__(256) void fused_kernel(
    const float* __restrict__ xt, const float* __restrict__ xt2,
    const float* __restrict__ yt,
    float* __restrict__ V, float* __restrict__ ymean, float* __restrict__ errt) {
  __shared__ float lds[LDSF];
  int bid = blockIdx.x, b = bid >> 5, d = bid & 31;
  int tid = threadIdx.x, lane = tid & 63, wv = tid >> 6;

  // ---- stage 7 contiguous rows (6 x_date cols + x) into LDS columns ----
  const float* xtb  = xt  + (size_t)(b * 192 + d * 6) * LL;
  const float* xtb2 = xt2 + (size_t)(b * DD + d) * LL;
  #pragma unroll
  for (int it = 0; it < 4; ++it) {
    int f = tid + it * 256;
    if (f < 896) {
      int c = f >> 7, c4 = f & 127;
      const float* srow = (c < 6) ? (xtb + (size_t)c * LL) : xtb2;
      float4 v = ((const float4*)srow)[c4];
      *(float4*)&lds[XCOL + c * CSTR + c4 * 4] = v;
    }
  }
  __syncthreads();

  // ---- sort 7 sequences (2 passes of 4 waves) ----
  #pragma unroll
  for (int pass = 0; pass < 2; ++pass) {
    int s = pass * 4 + wv;
    if (s < 7) {
      float v[8];
      const float4* colp = (const float4*)&lds[XCOL + s * CSTR + lane * 8];
      float4 c0 = colp[0], c1 = colp[1];
      v[0]=c0.x; v[1]=c0.y; v[2]=c0.z; v[3]=c0.w;
      v[4]=c1.x; v[5]=c1.y; v[6]=c1.z; v[7]=c1.w;
      sort512(v, lane);
      float e127 = __shfl(v[7], 15);
      float e128 = __shfl(v[0], 16);
      float e255 = __shfl(v[7], 31);
      float e383 = __shfl(v[7], 47);
      float e384 = __shfl(v[0], 48);
      if (lane == 0) {
        float q25 = e127 + 0.75f * (e128 - e127);   // 0.25*(n-1)=127.75
        float q75 = e383 + 0.25f * (e384 - e383);   // 0.75*(n-1)=383.25
        lds[MEDO + s] = e255;                       // torch lower-median
        lds[STDO + s] = q75 - q25 + 1e-6f;
      }
    }
  }
  __syncthreads();

  if (tid < 6) {
    float a = lds[STDO + 6] / lds[STDO + tid];
    lds[SAO + tid] = a;
    lds[SCO + tid] = lds[MEDO + 6] - lds[MEDO + tid] * a;
  }
  __syncthreads();

  float ask[6], csk[6];
  #pragma unroll
  for (int k = 0; k < 6; ++k) { ask[k] = lds[SAO + k]; csk[k] = lds[SCO + k]; }

  const float PSC = 0.58912435f;   // (1/sqrt(6)) * log2(e)

  // ---- transform rows tid, tid+256 into regs (f16-packed, x-side prescaled) ----
  float4 packed[2];
  #pragma unroll
  for (int it = 0; it < 2; ++it) {
    int l = tid + it * 256;
    float m0 = ask[0]*lds[XCOL+0*CSTR+l] + csk[0];
    float m1 = ask[1]*lds[XCOL+1*CSTR+l] + csk[1];
    float m2 = ask[2]*lds[XCOL+2*CSTR+l] + csk[2];
    float m3 = ask[3]*lds[XCOL+3*CSTR+l] + csk[3];
    float m4 = ask[4]*lds[XCOL+4*CSTR+l] + csk[4];
    float m5 = ask[5]*lds[XCOL+5*CSTR+l] + csk[5];
    float xvv = lds[XCOL + 6*CSTR + l];
    errt[(size_t)bid * LL + l] = xvv - (m0+m1+m2+m3+m4+m5) * (1.0f/6.0f);
    packed[it].x = asF(__builtin_amdgcn_cvt_pkrtz(m0*PSC, m1*PSC));
    packed[it].y = asF(__builtin_amdgcn_cvt_pkrtz(m2*PSC, m3*PSC));
    packed[it].z = asF(__builtin_amdgcn_cvt_pkrtz(m4*PSC, m5*PSC));
    packed[it].w = asF(__builtin_amdgcn_cvt_pkrtz(xvv, 0.0f));
  }

  // ---- y staging (threads 0..191): coalesced yt reads, map, ymean, pack ----
  float4 ypk; float ymv; bool doY = (tid < OO);
  if (doY) {
    const float2* yp = (const float2*)(yt + (size_t)(b * DD + d) * (OO * KK) + tid * 6);
    float2 y0 = yp[0], y1 = yp[1], y2 = yp[2];
    float q0 = ask[0]*y0.x + csk[0];
    float q1 = ask[1]*y0.y + csk[1];
    float q2 = ask[2]*y1.x + csk[2];
    float q3 = ask[3]*y1.y + csk[3];
    float q4 = ask[4]*y2.x + csk[4];
    float q5 = ask[5]*y2.y + csk[5];
    ymv = (q0+q1+q2+q3+q4+q5) * (1.0f/6.0f);
    ypk.x = asF(__builtin_amdgcn_cvt_pkrtz(q0, q1));
    ypk.y = asF(__builtin_amdgcn_cvt_pkrtz(q2, q3));
    ypk.z = asF(__builtin_amdgcn_cvt_pkrtz(q4, q5));
  }
  __syncthreads();   // all XCOL reads done; safe to overlay

  // ---- write f16 rows (overlay XCOL) + YDM; load yk frags ----
  *(float4*)&lds[tid * 4]         = packed[0];
  *(float4*)&lds[(tid + 256) * 4] = packed[1];
  if (doY) {
    ymean[(size_t)bid * OO + tid] = ymv;
    lds[YDMB + tid*4 + 0] = ypk.x;
    lds[YDMB + tid*4 + 1] = ypk.y;
    lds[YDMB + tid*4 + 2] = ypk.z;
  }
  __syncthreads();

  h2 yk[3][3];
  #pragma unroll
  for (int j = 0; j < 3; ++j) {
    int o = lane + 64 * j;
    yk[j][0] = asH(lds[YDMB + o*4 + 0]);
    yk[j][1] = asH(lds[YDMB + o*4 + 1]);
    yk[j][2] = asH(lds[YDMB + o*4 + 2]);
  }
  __syncthreads();   // yk loaded; DEN/NUM may overlay YDM after this

  // ---- attention: wave wv handles l in [wv*128, wv*128+128), 3 o's/lane ----
  float den[3] = {0.f,0.f,0.f}, num[3] = {0.f,0.f,0.f};
  int l0 = wv * 128;
  #pragma unroll 2
  for (int l = l0; l < l0 + 128; ++l) {
    float4 rw = *(const float4*)&lds[l * 4];
    h2 x01 = asH(rw.x), x23 = asH(rw.y), x45 = asH(rw.z);
    float xf = (float)(asH(rw.w).x);
    #pragma unroll
    for (int j = 0; j < 3; ++j) {
      float sc = __builtin_amdgcn_fdot2(x01, yk[j][0], 0.0f, false);
      sc = __builtin_amdgcn_fdot2(x23, yk[j][1], sc, false);
      sc = __builtin_amdgcn_fdot2(x45, yk[j][2], sc, false);
      float e = exp2f(sc);     // scale folded into x-side pack
      den[j] += e;
      num[j] += e * xf;
    }
  }
  #pragma unroll
  for (int j = 0; j < 3; ++j) {
    lds[YDMB + wv*192 + lane + 64*j]       = den[j];
    lds[YDMB + 768 + wv*192 + lane + 64*j] = num[j];
  }
  __syncthreads();
  if (tid < OO) {
    float dsum = lds[YDMB + tid] + lds[YDMB + 192 + tid]
               + lds[YDMB + 384 + tid] + lds[YDMB + 576 + tid];
    float nsum = lds[YDMB + 768 + tid] + lds[YDMB + 960 + tid]
               + lds[YDMB + 1152 + tid] + lds[YDMB + 1344 + tid];
    V[(size_t)bid * OO + tid] = nsum / dsum;
  }
}

// ---------------------------------------------------------------------------
// Gating MLP v3: 256 blocks x 512 threads (8 waves, 2/SIMD), 4 rows/block,
// thread owns hidden unit m=tid. err rows read as WAVE-UNIFORM scalar loads
// (s_load path, no LDS, no VMEM latency chain); w1 reads coalesced from
// L2-resident 1 MB. No register buffers -> no spills.
// ---------------------------------------------------------------------------
__global__ __launch_bounds__(512) void mlp_kernel(
    const float* __restrict__ errt, const float* __restrict__ w1,
    const float* __restrict__ b1, const float* __restrict__ w2,
    const float* __restrict__ b2, float* __restrict__ w0out) {
  int r0 = blockIdx.x * 4;
  int m = threadIdx.x;            // 0..511

  const float* e0 = errt + (size_t)(r0 + 0) * LL;
  const float* e1 = errt + (size_t)(r0 + 1) * LL;
  const float* e2 = errt + (size_t)(r0 + 2) * LL;
  const float* e3 = errt + (size_t)(r0 + 3) * LL;

  float bb1 = b1[m];
  float acc0 = bb1, acc1 = bb1, acc2 = bb1, acc3 = bb1;

  const float* wp = w1 + m;
  #pragma unroll 8
  for (int l = 0; l < LL; ++l) {
    float wv = wp[(size_t)l * DM];
    acc0 += e0[l] * wv;
    acc1 += e1[l] * wv;
    acc2 += e2[l] * wv;
    acc3 += e3[l] * wv;
  }

  float2 w2v = ((const float2*)w2)[m];
  float w2d = w2v.x - w2v.y;
  float p[4];
  {
    float g0 = 0.5f * acc0 * (1.0f + erff(acc0 * 0.70710678f));
    float g1 = 0.5f * acc1 * (1.0f + erff(acc1 * 0.70710678f));
    float g2 = 0.5f * acc2 * (1.0f + erff(acc2 * 0.70710678f));
    float g3 = 0.5f * acc3 * (1.0f + erff(acc3 * 0.70710678f));
    p[0] = g0 * w2d; p[1] = g1 * w2d; p[2] = g2 * w2d; p[3] = g3 * w2d;
  }

  #pragma unroll
  for (int r = 0; r < 4; ++r)
    for (int off = 32; off > 0; off >>= 1)
      p[r] += __shfl_down(p[r], off);

  __shared__ float part[8][4];
  int wave = m >> 6, lane = m & 63;
  if (lane == 0) {
    #pragma unroll
    for (int r = 0; r < 4; ++r) part[wave][r] = p[r];
  }
  __syncthreads();
  if (m < 4) {
    float ld = b2[0] - b2[1];
    #pragma unroll
    for (int wv = 0; wv < 8; ++wv) ld += part[wv][m];
    w0out[r0 + m] = 1.0f / (1.0f + expf(-ld));
  }
}

// ---------------------------------------------------------------------------
__global__ __launch_bounds__(256) void bnstats_kernel(
    const float* __restrict__ V, float* __restrict__ mu, float* __restrict__ rstd) {
  int d = blockIdx.x;
  int tid = threadIdx.x;
  float s = 0.0f, s2 = 0.0f;
  for (int idx = tid; idx < BB * OO; idx += 256) {
    int b = idx / OO, o = idx - b * OO;
    float v = V[((size_t)b * DD + d) * OO + o];
    s += v; s2 += v * v;
  }
  for (int off = 32; off > 0; off >>= 1) {
    s  += __shfl_down(s, off);
    s2 += __shfl_down(s2, off);
  }
  __shared__ float ps[4], ps2[4];
  int wave = tid >> 6, lane = tid & 63;
  if (lane == 0) { ps[wave] = s; ps2[wave] = s2; }
  __syncthreads();
  if (tid == 0) {
    float S = ps[0] + ps[1] + ps[2] + ps[3];
    float S2 = ps2[0] + ps2[1] + ps2[2] + ps2[3];
    const float inv = 1.0f / (BB * OO);
    float mean = S * inv;
    float var = S2 * inv - mean * mean;
    mu[d] = mean;
    rstd[d] = rsqrtf(var + 1e-5f);
  }
}

// ---------------------------------------------------------------------------
// Final fusion via LDS transpose: coalesced reads AND writes.
// 64 blocks: (b, o-half of 96).
// ---------------------------------------------------------------------------
__global__ __launch_bounds__(256) void final_kernel(
    const float* __restrict__ V, const float* __restrict__ ymean,
    const float* __restrict__ w0, const float* __restrict__ mu,
    const float* __restrict__ rstd, const float* __restrict__ gamma,
    const float* __restrict__ beta, float* __restrict__ out) {
  __shared__ float vsh[32 * 100], ysh[32 * 100];
  __shared__ float gate[32], scal[32], offs[32];
  int bid = blockIdx.x, b = bid >> 1, o0 = (bid & 1) * 96;
  int tid = threadIdx.x;

  #pragma unroll
  for (int it = 0; it < 3; ++it) {        // 32 d x 24 float4
    int f = tid + it * 256;
    int d = f / 24, c4 = f % 24;
    size_t goff = (size_t)(b * DD + d) * OO + o0;
    float4 v = ((const float4*)(V + goff))[c4];
    float4 y = ((const float4*)(ymean + goff))[c4];
    float* pv = &vsh[d * 100 + c4 * 4];
    float* py = &ysh[d * 100 + c4 * 4];
    pv[0]=v.x; pv[1]=v.y; pv[2]=v.z; pv[3]=v.w;
    py[0]=y.x; py[1]=y.y; py[2]=y.z; py[3]=y.w;
  }
  if (tid < 32) {
    float g = gamma[tid] * rstd[tid];
    gate[tid] = w0[b * DD + tid];
    scal[tid] = g;
    offs[tid] = beta[tid] - mu[tid] * g;
  }
  __syncthreads();

  #pragma unroll
  for (int it = 0; it < 3; ++it) {        // 96 o x 8 float4
    int f = tid + it * 256;
    int op = f / 8, c4 = f % 8;
    float4 r;
    #pragma unroll
    for (int j = 0; j < 4; ++j) {
      int d = c4 * 4 + j;
      float v  = vsh[d * 100 + op];
      float ym = ysh[d * 100 + op];
      float g  = gate[d];
      float y  = v * scal[d] + offs[d];
      ((float*)&r)[j] = ym * g + y * (1.0f - g);
    }
    ((float4*)(out + (size_t)(b * OO + o0 + op) * DD))[c4] = r;
  }
}

// ---------------------------------------------------------------------------
extern "C" void kernel_launch(void* const* d_in, const int* in_sizes, int n_in,
                              void* d_out, int out_size, void* d_ws, size_t ws_size,
                              hipStream_t stream) {
  const float* x      = (const float*)d_in[0];
  const float* x_date = (const float*)d_in[1];
  const float* y_date = (const float*)d_in[2];
  const float* w1     = (const float*)d_in[3];
  const float* b1     = (const float*)d_in[4];
  const float* w2     = (const float*)d_in[5];
  const float* b2     = (const float*)d_in[6];
  const float* gamma  = (const float*)d_in[7];
  const float* beta   = (const float*)d_in[8];
  float* out = (float*)d_out;

  float* ws    = (float*)d_ws;
  float* V     = ws;                 // 196608  (B,D,O)
  float* ymean = ws + 196608;        // 196608  (B,D,O)
  float* errt  = ws + 393216;        // 524288  (B,D,L)
  float* w0    = ws + 917504;        // 1024    (B,D)
  float* mu    = ws + 918528;        // 32
  float* rstd  = ws + 918560;        // 32
  float* xt    = ws + 918592;        // 3145728 (B,192,L)
  float* xt2   = ws + 4064320;       // 524288  (B,D,L)
  float* yt    = ws + 4588608;       // 1179648 (B,D,O,K)

  prep_kernel<<<768, 256, 0, stream>>>(x, x_date, y_date, xt, xt2, yt);
  fused_kernel<<<BB * DD, 256, 0, stream>>>(xt, xt2, yt, V, ymean, errt);
  mlp_kernel<<<BB * DD / 4, 512, 0, stream>>>(errt, w1, b1, w2, b2, w0);
  bnstats_kernel<<<DD, 256, 0, stream>>>(V, mu, rstd);
  final_kernel<<<2 * BB, 256, 0, stream>>>(V, ymean, w0, mu, rstd, gamma, beta, out);
}

// Round 7
// 171.077 us; speedup vs baseline: 1.5630x; 1.0075x over previous
//
#include <hip/hip_runtime.h>
#include <math.h>

#define BB 32
#define LL 512
#define DD 32
#define KK 6
#define OO 192
#define DM 512

typedef __fp16 h2 __attribute__((ext_vector_type(2)));
union F2H { float f; h2 h; };
__device__ __forceinline__ float asF(h2 h) { F2H u; u.h = h; return u.f; }

typedef __fp16 h8v __attribute__((ext_vector_type(8)));
typedef float f4v __attribute__((ext_vector_type(4)));
union F4H8 { float4 f; h8v h; };
__device__ __forceinline__ h8v toh8(float4 v) { F4H8 u; u.f = v; return u.h; }

#define MOVDPP(x, ctrl) \
  __int_as_float(__builtin_amdgcn_mov_dpp(__float_as_int(x), ctrl, 0xf, 0xf, true))

// LDS layout (float slots) for fused kernel
#define CSTR  520
#define XCOL  0                 // 7 cols x 520 f32 during stats; cols0-3 overlaid by AROW
#define AROW  0                 // 512 rows x 4 slots (8 f16: k0..5, xv, 0)
#define XV    3120              // = XCOL + 6*CSTR : x as f32 (kept in place)
#define YROW  3648              // 192 rows x 4 slots (8 f16: q0..5, 0, 0)
#define DENB  4416              // 4 x 192
#define NUMB  5184              // 4 x 192
#define MEDO  5952
#define STDO  5959
#define SAO   5966
#define SCO   5972
#define LDSF  5984              // 23.9 KB

// ---------------------------------------------------------------------------
// Prep: coalesced tiled transposes.
//  S1 (512 blocks): x_date (b,l,dk)   -> xt  (b,dk,l)   [dk=d*6+k, 192]
//  S2 (128 blocks): x      (b,l,d)    -> xt2 (b,d,l)
//  S3 (128 blocks): y_date (b,o,dk)   -> yt  (b,d,o,k)
// ---------------------------------------------------------------------------
__global__ __launch_bounds__(256) void prep_kernel(
    const float* __restrict__ x, const float* __restrict__ x_date,
    const float* __restrict__ y_date,
    float* __restrict__ xt, float* __restrict__ xt2, float* __restrict__ yt) {
  __shared__ float tl[9408];
  int bid = blockIdx.x, tid = threadIdx.x;

  if (bid < 512) {
    int b = bid >> 4, l0 = (bid & 15) * 32;
    const float* src = x_date + (size_t)(b * LL + l0) * 192;
    #pragma unroll
    for (int it = 0; it < 6; ++it) {
      int f = tid + it * 256;
      int row = f / 48, c4 = f % 48;
      float4 v = ((const float4*)(src + (size_t)row * 192))[c4];
      float* p = &tl[row * 196 + c4 * 4];
      p[0] = v.x; p[1] = v.y; p[2] = v.z; p[3] = v.w;
    }
    __syncthreads();
    #pragma unroll
    for (int it = 0; it < 6; ++it) {
      int f = tid + it * 256;
      int dk = f / 8, c4 = f % 8;
      float4 v;
      v.x = tl[(c4 * 4 + 0) * 196 + dk];
      v.y = tl[(c4 * 4 + 1) * 196 + dk];
      v.z = tl[(c4 * 4 + 2) * 196 + dk];
      v.w = tl[(c4 * 4 + 3) * 196 + dk];
      ((float4*)(xt + (size_t)(b * 192 + dk) * LL + l0))[c4] = v;
    }
  } else if (bid < 640) {
    int id = bid - 512;
    int b = id >> 2, l0 = (id & 3) * 128;
    const float* src = x + (size_t)(b * LL + l0) * DD;
    #pragma unroll
    for (int it = 0; it < 4; ++it) {
      int f = tid + it * 256;
      int row = f / 8, c4 = f % 8;
      float4 v = ((const float4*)src)[f];
      float* p = &tl[row * 36 + c4 * 4];
      p[0] = v.x; p[1] = v.y; p[2] = v.z; p[3] = v.w;
    }
    __syncthreads();
    #pragma unroll
    for (int it = 0; it < 4; ++it) {
      int f = tid + it * 256;
      int d = f / 32, c4 = f % 32;
      float4 v;
      v.x = tl[(c4 * 4 + 0) * 36 + d];
      v.y = tl[(c4 * 4 + 1) * 36 + d];
      v.z = tl[(c4 * 4 + 2) * 36 + d];
      v.w = tl[(c4 * 4 + 3) * 36 + d];
      ((float4*)(xt2 + (size_t)(b * DD + d) * LL + l0))[c4] = v;
    }
  } else {
    int id = bid - 640;
    int b = id >> 2, o0 = (id & 3) * 48;
    const float* src = y_date + (size_t)(b * OO + o0) * 192;
    #pragma unroll
    for (int it = 0; it < 9; ++it) {
      int f = tid + it * 256;
      int row = f / 48, c4 = f % 48;
      float4 v = ((const float4*)(src + (size_t)row * 192))[c4];
      float* p = &tl[row * 196 + c4 * 4];
      p[0] = v.x; p[1] = v.y; p[2] = v.z; p[3] = v.w;
    }
    __syncthreads();
    #pragma unroll
    for (int it = 0; it < 9; ++it) {
      int f = tid + it * 256;
      int d = f / 72, r4 = f % 72;
      float4 v;
      #pragma unroll
      for (int j = 0; j < 4; ++j) {
        int e = r4 * 4 + j;
        int op = e / 6, k = e - op * 6;
        ((float*)&v)[j] = tl[op * 196 + d * 6 + k];
      }
      ((float4*)(yt + (size_t)(b * DD + d) * (OO * KK) + o0 * 6))[r4] = v;
    }
  }
}

// ---------------------------------------------------------------------------
// In-register bitonic sort of 512 floats across one wave (8 elems/lane).
// Cross-lane xor 1/2/8 via DPP (VALU pipe); 4/16/32 via shfl (LDS pipe).
// ---------------------------------------------------------------------------
__device__ __forceinline__ void sort512(float v[8], int lane) {
  #pragma unroll
  for (int k = 2; k <= 512; k <<= 1) {
    #pragma unroll
    for (int j = k >> 1; j > 0; j >>= 1) {
      if (j >= 8) {
        int jj = j >> 3;
        bool lower = (lane & jj) == 0;
        bool asc = ((lane << 3) & k) == 0;
        bool keepmin = (asc == lower);
        #pragma unroll
        for (int r = 0; r < 8; ++r) {
          float o;
          if (jj == 1)      o = MOVDPP(v[r], 0xB1);   // quad_perm [1,0,3,2]
          else if (jj == 2) o = MOVDPP(v[r], 0x4E);   // quad_perm [2,3,0,1]
          else if (jj == 8) o = MOVDPP(v[r], 0x128);  // row_ror:8 == xor8
          else              o = __shfl_xor(v[r], jj);
          v[r] = keepmin ? fminf(v[r], o) : fmaxf(v[r], o);
        }
      } else {
        #pragma unroll
        for (int r = 0; r < 8; ++r) {
          if ((r & j) == 0) {
            int r2 = r | j;
            bool asc = (((lane << 3) | r) & k) == 0;
            float a = v[r], b = v[r2];
            float lo = fminf(a, b), hi = fmaxf(a, b);
            v[r]  = asc ? lo : hi;
            v[r2] = asc ? hi : lo;
          }
        }
      }
    }
  }
}

// ---------------------------------------------------------------------------
// Fused: per-(b,d) order stats + affine map + MFMA attention + err + ymean.
// ---------------------------------------------------------------------------
__global__ __launch_bounds__(256) void fused_kernel(
    const float* __restrict__ xt, const float* __restrict__ xt2,
    const float* __restrict__ yt,
    float* __restrict__ V, float* __restrict__ ymean, float* __restrict__ errt) {
  __shared__ float lds[LDSF];
  int bid = blockIdx.x, b = bid >> 5, d = bid & 31;
  int tid = threadIdx.x, lane = tid & 63, wv = tid >> 6;

  // ---- stage 7 contiguous rows (6 x_date cols + x) into LDS columns ----
  const float* xtb  = xt  + (size_t)(b * 192 + d * 6) * LL;
  const float* xtb2 = xt2 + (size_t)(b * DD + d) * LL;
  #pragma unroll
  for (int it = 0; it < 4; ++it) {
    int f = tid + it * 256;
    if (f < 896) {
      int c = f >> 7, c4 = f & 127;
      const float* srow = (c < 6) ? (xtb + (size_t)c * LL) : xtb2;
      float4 v = ((const float4*)srow)[c4];
      *(float4*)&lds[XCOL + c * CSTR + c4 * 4] = v;
    }
  }
  __syncthreads();

  // ---- sort 7 sequences (2 passes of 4 waves) ----
  #pragma unroll
  for (int pass = 0; pass < 2; ++pass) {
    int s = pass * 4 + wv;
    if (s < 7) {
      float v[8];
      const float4* colp = (const float4*)&lds[XCOL + s * CSTR + lane * 8];
      float4 c0 = colp[0], c1 = colp[1];
      v[0]=c0.x; v[1]=c0.y; v[2]=c0.z; v[3]=c0.w;
      v[4]=c1.x; v[5]=c1.y; v[6]=c1.z; v[7]=c1.w;
      sort512(v, lane);
      float e127 = __shfl(v[7], 15);
      float e128 = __shfl(v[0], 16);
      float e255 = __shfl(v[7], 31);
      float e383 = __shfl(v[7], 47);
      float e384 = __shfl(v[0], 48);
      if (lane == 0) {
        float q25 = e127 + 0.75f * (e128 - e127);   // 0.25*(n-1)=127.75
        float q75 = e383 + 0.25f * (e384 - e383);   // 0.75*(n-1)=383.25
        lds[MEDO + s] = e255;                       // torch lower-median
        lds[STDO + s] = q75 - q25 + 1e-6f;
      }
    }
  }
  __syncthreads();

  if (tid < 6) {
    float a = lds[STDO + 6] / lds[STDO + tid];
    lds[SAO + tid] = a;
    lds[SCO + tid] = lds[MEDO + 6] - lds[MEDO + tid] * a;
  }
  __syncthreads();

  float ask[6], csk[6];
  #pragma unroll
  for (int k = 0; k < 6; ++k) { ask[k] = lds[SAO + k]; csk[k] = lds[SCO + k]; }

  const float PSC = 0.58912435f;   // (1/sqrt(6)) * log2(e)

  // ---- transform rows tid, tid+256 into regs (f16-packed, x-side prescaled) ----
  float4 packed[2];
  #pragma unroll
  for (int it = 0; it < 2; ++it) {
    int l = tid + it * 256;
    float m0 = ask[0]*lds[XCOL+0*CSTR+l] + csk[0];
    float m1 = ask[1]*lds[XCOL+1*CSTR+l] + csk[1];
    float m2 = ask[2]*lds[XCOL+2*CSTR+l] + csk[2];
    float m3 = ask[3]*lds[XCOL+3*CSTR+l] + csk[3];
    float m4 = ask[4]*lds[XCOL+4*CSTR+l] + csk[4];
    float m5 = ask[5]*lds[XCOL+5*CSTR+l] + csk[5];
    float xvv = lds[XV + l];
    errt[(size_t)bid * LL + l] = xvv - (m0+m1+m2+m3+m4+m5) * (1.0f/6.0f);
    packed[it].x = asF(__builtin_amdgcn_cvt_pkrtz(m0*PSC, m1*PSC));
    packed[it].y = asF(__builtin_amdgcn_cvt_pkrtz(m2*PSC, m3*PSC));
    packed[it].z = asF(__builtin_amdgcn_cvt_pkrtz(m4*PSC, m5*PSC));
    packed[it].w = 0.0f;            // A slots 6,7 x B pad(=0) -> no contribution
  }

  // ---- y staging (threads 0..191): coalesced yt reads, map, ymean, pack ----
  float4 ypk; float ymv; bool doY = (tid < OO);
  if (doY) {
    const float2* yp = (const float2*)(yt + (size_t)(b * DD + d) * (OO * KK) + tid * 6);
    float2 y0 = yp[0], y1 = yp[1], y2 = yp[2];
    float q0 = ask[0]*y0.x + csk[0];
    float q1 = ask[1]*y0.y + csk[1];
    float q2 = ask[2]*y1.x + csk[2];
    float q3 = ask[3]*y1.y + csk[3];
    float q4 = ask[4]*y2.x + csk[4];
    float q5 = ask[5]*y2.y + csk[5];
    ymv = (q0+q1+q2+q3+q4+q5) * (1.0f/6.0f);
    ypk.x = asF(__builtin_amdgcn_cvt_pkrtz(q0, q1));
    ypk.y = asF(__builtin_amdgcn_cvt_pkrtz(q2, q3));
    ypk.z = asF(__builtin_amdgcn_cvt_pkrtz(q4, q5));
    ypk.w = 0.0f;                   // B pad MUST be zero
  }
  __syncthreads();   // all XCOL col0-5 reads done; safe to overlay AROW

  *(float4*)&lds[AROW + tid * 4]         = packed[0];
  *(float4*)&lds[AROW + (tid + 256) * 4] = packed[1];
  if (doY) {
    ymean[(size_t)bid * OO + tid] = ymv;
    *(float4*)&lds[YROW + tid * 4] = ypk;
  }
  __syncthreads();

  // ---- MFMA attention: wave wv owns l in [wv*128, +128) = 8 l-tiles ----
  int m16 = lane & 15, quad = lane >> 4;
  f4v zc = {0.f, 0.f, 0.f, 0.f};

  h8v bfr[12];
  #pragma unroll
  for (int ot = 0; ot < 12; ++ot) {
    float4 tb = {0.f, 0.f, 0.f, 0.f};
    if (quad == 0) tb = *(const float4*)&lds[YROW + (ot * 16 + m16) * 4];
    bfr[ot] = toh8(tb);
  }

  float den[12], num[12];
  #pragma unroll
  for (int ot = 0; ot < 12; ++ot) { den[ot] = 0.f; num[ot] = 0.f; }

  int l0 = wv * 128;
  #pragma unroll 2
  for (int lt = 0; lt < 8; ++lt) {
    float4 ta = {0.f, 0.f, 0.f, 0.f};
    if (quad == 0) ta = *(const float4*)&lds[AROW + (l0 + lt * 16 + m16) * 4];
    h8v afr = toh8(ta);
    float4 xq = *(const float4*)&lds[XV + l0 + lt * 16 + quad * 4];
    float xr[4] = {xq.x, xq.y, xq.z, xq.w};
    #pragma unroll
    for (int ot = 0; ot < 12; ++ot) {
      f4v c = __builtin_amdgcn_mfma_f32_16x16x32_f16(afr, bfr[ot], zc, 0, 0, 0);
      #pragma unroll
      for (int r = 0; r < 4; ++r) {
        float e = exp2f(c[r]);      // scale folded into A-side pack
        den[ot] += e;
        num[ot] += e * xr[r];
      }
    }
  }

  // quad reduction (rows) then cross-wave partials
  #pragma unroll
  for (int ot = 0; ot < 12; ++ot) {
    float ds = den[ot], ns = num[ot];
    ds += __shfl_xor(ds, 16); ds += __shfl_xor(ds, 32);
    ns += __shfl_xor(ns, 16); ns += __shfl_xor(ns, 32);
    if (quad == 0) {
      lds[DENB + wv * 192 + ot * 16 + m16] = ds;
      lds[NUMB + wv * 192 + ot * 16 + m16] = ns;
    }
  }
  __syncthreads();
  if (tid < OO) {
    float dsum = lds[DENB + tid] + lds[DENB + 192 + tid]
               + lds[DENB + 384 + tid] + lds[DENB + 576 + tid];
    float nsum = lds[NUMB + tid] + lds[NUMB + 192 + tid]
               + lds[NUMB + 384 + tid] + lds[NUMB + 576 + tid];
    V[(size_t)bid * OO + tid] = nsum / dsum;
  }
}

// ---------------------------------------------------------------------------
// Gating MLP: 256 blocks x 512 threads, 4 rows/block; err rows wave-uniform
// scalar loads, w1 coalesced from L2.
// ---------------------------------------------------------------------------
__global__ __launch_bounds__(512) void mlp_kernel(
    const float* __restrict__ errt, const float* __restrict__ w1,
    const float* __restrict__ b1, const float* __restrict__ w2,
    const float* __restrict__ b2, float* __restrict__ w0out) {
  int r0 = blockIdx.x * 4;
  int m = threadIdx.x;

  const float* e0 = errt + (size_t)(r0 + 0) * LL;
  const float* e1 = errt + (size_t)(r0 + 1) * LL;
  const float* e2 = errt + (size_t)(r0 + 2) * LL;
  const float* e3 = errt + (size_t)(r0 + 3) * LL;

  float bb1 = b1[m];
  float acc0 = bb1, acc1 = bb1, acc2 = bb1, acc3 = bb1;

  const float* wp = w1 + m;
  #pragma unroll 8
  for (int l = 0; l < LL; ++l) {
    float wvv = wp[(size_t)l * DM];
    acc0 += e0[l] * wvv;
    acc1 += e1[l] * wvv;
    acc2 += e2[l] * wvv;
    acc3 += e3[l] * wvv;
  }

  float2 w2v = ((const float2*)w2)[m];
  float w2d = w2v.x - w2v.y;
  float p[4];
  {
    float g0 = 0.5f * acc0 * (1.0f + erff(acc0 * 0.70710678f));
    float g1 = 0.5f * acc1 * (1.0f + erff(acc1 * 0.70710678f));
    float g2 = 0.5f * acc2 * (1.0f + erff(acc2 * 0.70710678f));
    float g3 = 0.5f * acc3 * (1.0f + erff(acc3 * 0.70710678f));
    p[0] = g0 * w2d; p[1] = g1 * w2d; p[2] = g2 * w2d; p[3] = g3 * w2d;
  }

  #pragma unroll
  for (int r = 0; r < 4; ++r)
    for (int off = 32; off > 0; off >>= 1)
      p[r] += __shfl_down(p[r], off);

  __shared__ float part[8][4];
  int wave = m >> 6, lane = m & 63;
  if (lane == 0) {
    #pragma unroll
    for (int r = 0; r < 4; ++r) part[wave][r] = p[r];
  }
  __syncthreads();
  if (m < 4) {
    float ld = b2[0] - b2[1];
    #pragma unroll
    for (int wvi = 0; wvi < 8; ++wvi) ld += part[wvi][m];
    w0out[r0 + m] = 1.0f / (1.0f + expf(-ld));
  }
}

// ---------------------------------------------------------------------------
__global__ __launch_bounds__(256) void bnstats_kernel(
    const float* __restrict__ V, float* __restrict__ mu, float* __restrict__ rstd) {
  int d = blockIdx.x;
  int tid = threadIdx.x;
  float s = 0.0f, s2 = 0.0f;
  for (int idx = tid; idx < BB * OO; idx += 256) {
    int b = idx / OO, o = idx - b * OO;
    float v = V[((size_t)b * DD + d) * OO + o];
    s += v; s2 += v * v;
  }
  for (int off = 32; off > 0; off >>= 1) {
    s  += __shfl_down(s, off);
    s2 += __shfl_down(s2, off);
  }
  __shared__ float ps[4], ps2[4];
  int wave = tid >> 6, lane = tid & 63;
  if (lane == 0) { ps[wave] = s; ps2[wave] = s2; }
  __syncthreads();
  if (tid == 0) {
    float S = ps[0] + ps[1] + ps[2] + ps[3];
    float S2 = ps2[0] + ps2[1] + ps2[2] + ps2[3];
    const float inv = 1.0f / (BB * OO);
    float mean = S * inv;
    float var = S2 * inv - mean * mean;
    mu[d] = mean;
    rstd[d] = rsqrtf(var + 1e-5f);
  }
}

// ---------------------------------------------------------------------------
// Final fusion via LDS transpose: coalesced reads AND writes.
// ---------------------------------------------------------------------------
__global__ __launch_bounds__(256) void final_kernel(
    const float* __restrict__ V, const float* __restrict__ ymean,
    const float* __restrict__ w0, const float* __restrict__ mu,
    const float* __restrict__ rstd, const float* __restrict__ gamma,
    const float* __restrict__ beta, float* __restrict__ out) {
  __shared__ float vsh[32 * 100], ysh[32 * 100];
  __shared__ float gate[32], scal[32], offs[32];
  int bid = blockIdx.x, b = bid >> 1, o0 = (bid & 1) * 96;
  int tid = threadIdx.x;

  #pragma unroll
  for (int it = 0; it < 3; ++it) {
    int f = tid + it * 256;
    int d = f / 24, c4 = f % 24;
    size_t goff = (size_t)(b * DD + d) * OO + o0;
    float4 v = ((const float4*)(V + goff))[c4];
    float4 y = ((const float4*)(ymean + goff))[c4];
    float* pv = &vsh[d * 100 + c4 * 4];
    float* py = &ysh[d * 100 + c4 * 4];
    pv[0]=v.x; pv[1]=v.y; pv[2]=v.z; pv[3]=v.w;
    py[0]=y.x; py[1]=y.y; py[2]=y.z; py[3]=y.w;
  }
  if (tid < 32) {
    float g = gamma[tid] * rstd[tid];
    gate[tid] = w0[b * DD + tid];
    scal[tid] = g;
    offs[tid] = beta[tid] - mu[tid] * g;
  }
  __syncthreads();

  #pragma unroll
  for (int it = 0; it < 3; ++it) {
    int f = tid + it * 256;
    int op = f / 8, c4 = f % 8;
    float4 r;
    #pragma unroll
    for (int j = 0; j < 4; ++j) {
      int d = c4 * 4 + j;
      float v  = vsh[d * 100 + op];
      float ym = ysh[d * 100 + op];
      float g  = gate[d];
      float y  = v * scal[d] + offs[d];
      ((float*)&r)[j] = ym * g + y * (1.0f - g);
    }
    ((float4*)(out + (size_t)(b * OO + o0 + op) * DD))[c4] = r;
  }
}

// ---------------------------------------------------------------------------
extern "C" void kernel_launch(void* const* d_in, const int* in_sizes, int n_in,
                              void* d_out, int out_size, void* d_ws, size_t ws_size,
                              hipStream_t stream) {
  const float* x      = (const float*)d_in[0];
  const float* x_date = (const float*)d_in[1];
  const float* y_date = (const float*)d_in[2];
  const float* w1     = (const float*)d_in[3];
  const float* b1     = (const float*)d_in[4];
  const float* w2     = (const float*)d_in[5];
  const float* b2     = (const float*)d_in[6];
  const float* gamma  = (const float*)d_in[7];
  const float* beta   = (const float*)d_in[8];
  float* out = (float*)d_out;

  float* ws    = (float*)d_ws;
  float* V     = ws;                 // 196608  (B,D,O)
  float* ymean = ws + 196608;        // 196608  (B,D,O)
  float* errt  = ws + 393216;        // 524288  (B,D,L)
  float* w0    = ws + 917504;        // 1024    (B,D)
  float* mu    = ws + 918528;        // 32
  float* rstd  = ws + 918560;        // 32
  float* xt    = ws + 918592;        // 3145728 (B,192,L)
  float* xt2   = ws + 4064320;       // 524288  (B,D,L)
  float* yt    = ws + 4588608;       // 1179648 (B,D,O,K)

  prep_kernel<<<768, 256, 0, stream>>>(x, x_date, y_date, xt, xt2, yt);
  fused_kernel<<<BB * DD, 256, 0, stream>>>(xt, xt2, yt, V, ymean, errt);
  mlp_kernel<<<BB * DD / 4, 512, 0, stream>>>(errt, w1, b1, w2, b2, w0);
  bnstats_kernel<<<DD, 256, 0, stream>>>(V, mu, rstd);
  final_kernel<<<2 * BB, 256, 0, stream>>>(V, ymean, w0, mu, rstd, gamma, beta, out);
}